// Round 7
// baseline (651.151 us; speedup 1.0000x reference)
//
#include <hip/hip_runtime.h>
#include <cstddef>
#include <cstdint>

#define LRELU(v) ((v) > 0.f ? (v) : 0.2f * (v))

// ================= K1: fused gemm1 + fold(W2,a2) + deg/done init =================

__global__ __launch_bounds__(256) void k_front(const float* __restrict__ x,
                                               const float* __restrict__ W1,
                                               const float* __restrict__ a_src1,
                                               const float* __restrict__ a_dst1,
                                               const float* __restrict__ W2,
                                               const float* __restrict__ a_src2,
                                               const float* __restrict__ a_dst2,
                                               float* h1, float* as1, float* ad1,
                                               float* wfold, int* deg, int* done,
                                               int N, int GB) {
    int t = threadIdx.x;
    int b = blockIdx.x;
    if (b < GB) {
        __shared__ float xs[16][128];
        int n0 = b * 16;
#pragma unroll
        for (int i = 0; i < 2; i++) {
            int idx = (t + i * 256) * 4;
            int r = idx >> 7, c = idx & 127;
            int n = n0 + r;
            float4 v = make_float4(0.f, 0.f, 0.f, 0.f);
            if (n < N) v = *(const float4*)&x[(size_t)n * 128 + c];
            *(float4*)&xs[r][c] = v;
        }
        __syncthreads();
        int wv = t >> 6, lane = t & 63;
        int m0 = wv * 4;
        float acc[4] = {0.f, 0.f, 0.f, 0.f};
        for (int k0 = 0; k0 < 128; k0 += 4) {
            float w0 = W1[(k0 + 0) * 64 + lane];
            float w1 = W1[(k0 + 1) * 64 + lane];
            float w2 = W1[(k0 + 2) * 64 + lane];
            float w3 = W1[(k0 + 3) * 64 + lane];
#pragma unroll
            for (int mi = 0; mi < 4; mi++) {
                float4 a = *(const float4*)&xs[m0 + mi][k0];
                acc[mi] += a.x * w0 + a.y * w1 + a.z * w2 + a.w * w3;
            }
        }
        float was = a_src1[lane], wad = a_dst1[lane];
#pragma unroll
        for (int mi = 0; mi < 4; mi++) {
            int n = n0 + m0 + mi;
            if (n >= N) break;
            h1[(size_t)n * 64 + lane] = acc[mi];
            float ps = acc[mi] * was, pd = acc[mi] * wad;
            ps += __shfl_xor(ps, 1); ps += __shfl_xor(ps, 2); ps += __shfl_xor(ps, 4);
            pd += __shfl_xor(pd, 1); pd += __shfl_xor(pd, 2); pd += __shfl_xor(pd, 4);
            if ((lane & 7) == 0) {
                as1[n * 8 + (lane >> 3)] = ps;
                ad1[n * 8 + (lane >> 3)] = pd;
            }
        }
    } else if (b < GB + 64) {
        int k = b - GB;
        int c0 = t * 4;
        int h = t >> 5;
        float4 w = *(const float4*)&W2[(size_t)k * 1024 + c0];
        float4 s4 = *(const float4*)&a_src2[c0];
        float4 d4 = *(const float4*)&a_dst2[c0];
        float ss = w.x * s4.x + w.y * s4.y + w.z * s4.z + w.w * s4.w;
        float sd = w.x * d4.x + w.y * d4.y + w.z * d4.z + w.w * d4.w;
#pragma unroll
        for (int off = 1; off <= 16; off <<= 1) {
            ss += __shfl_xor(ss, off);
            sd += __shfl_xor(sd, off);
        }
        if ((t & 31) == 0) {
            wfold[k * 8 + h] = ss;
            wfold[512 + k * 8 + h] = sd;
        }
    } else {
        int i = (b - GB - 64) * 256 + t;
        if (i < N) deg[i] = 1;  // self-loop
        if (b == GB + 64 && t == 0) *done = 0;
    }
}

// ================= histogram + (last block) exclusive scan =================

__global__ __launch_bounds__(256) void k_histscan(const int* __restrict__ src,
                                                  const int* __restrict__ dst,
                                                  int* deg, int* done,
                                                  int* offs, int* cursor, int E, int N) {
    __shared__ int part[256];
    __shared__ int islast;
    int t = threadIdx.x;
    int e = blockIdx.x * 256 + t;
    if (e < E) {
        int s = src[e], d = dst[e];
        if (s != d) atomicAdd(&deg[d], 1);  // masked self-edges dropped
    }
    __syncthreads();
    if (t == 0) {
        int old = __hip_atomic_fetch_add(done, 1, __ATOMIC_ACQ_REL, __HIP_MEMORY_SCOPE_AGENT);
        islast = (old == (int)gridDim.x - 1);
    }
    __syncthreads();
    if (!islast) return;
    int chunk = (N + 255) >> 8;
    int start = t * chunk;
    int s = 0;
    for (int i = 0; i < chunk; i++) {
        int idx = start + i;
        if (idx < N)
            s += __hip_atomic_load(&deg[idx], __ATOMIC_RELAXED, __HIP_MEMORY_SCOPE_AGENT);
    }
    part[t] = s;
    __syncthreads();
    for (int off = 1; off < 256; off <<= 1) {
        int v = (t >= off) ? part[t - off] : 0;
        __syncthreads();
        part[t] += v;
        __syncthreads();
    }
    int run = part[t] - s;
    for (int i = 0; i < chunk; i++) {
        int idx = start + i;
        if (idx < N) {
            int d = __hip_atomic_load(&deg[idx], __ATOMIC_RELAXED, __HIP_MEMORY_SCOPE_AGENT);
            offs[idx] = run;
            cursor[idx] = run;
            run += d;
        }
    }
    if (t == 255) offs[N] = part[255];
}

// ================= CSR fill =================

__global__ void k_fill(const int* src, const int* dst, int* cursor, int* csr, int E, int N) {
    int e = blockIdx.x * blockDim.x + threadIdx.x;
    if (e < E) {
        int s = src[e], d = dst[e];
        if (s != d) {
            int pos = atomicAdd(&cursor[d], 1);
            csr[pos] = s;
        }
    } else if (e < E + N) {
        int i = e - E;
        int pos = atomicAdd(&cursor[i], 1);
        csr[pos] = i;
    }
}

// ================= fused attention+aggregation, layer 1 =================

__global__ __launch_bounds__(256) void k_attn1(const int* offs, const int* csr,
                                               const float* __restrict__ h1,
                                               const float* __restrict__ as1,
                                               const float* __restrict__ ad1,
                                               const float* __restrict__ b1,
                                               const float* __restrict__ wfold,
                                               float* z, float* as2, float* ad2, int N) {
    __shared__ float al[4][512];
    __shared__ int   sc[4][64];
    __shared__ float zr[4][64];
    int w = threadIdx.x >> 6, lane = threadIdx.x & 63;
    int node = blockIdx.x * 4 + w;
    if (node >= N) return;
    int el = lane >> 3, h = lane & 7;
    int beg = offs[node], end = offs[node + 1];
    int degN = end - beg;
    float adv = ad1[node * 8 + h];
    float m = -1e30f, l = 0.f;
    for (int it = 0; it * 8 < degN; it++) {
        int j = beg + it * 8 + el;
        float e = -1e30f;
        int s = 0;
        if (j < end) {
            s = csr[j];
            float v = as1[s * 8 + h] + adv;
            e = LRELU(v);
        }
        if (it < 8) {
            al[w][it * 64 + lane] = e;
            if (h == 0 && j < end) sc[w][it * 8 + el] = s;
        }
        float nm = fmaxf(m, e);
        l = l * __expf(m - nm) + ((j < end) ? __expf(e - nm) : 0.f);
        m = nm;
    }
#pragma unroll
    for (int off = 8; off < 64; off <<= 1) {
        float m2 = __shfl_xor(m, off), l2 = __shfl_xor(l, off);
        float nm = fmaxf(m, m2);
        l = l * __expf(m - nm) + l2 * __expf(m2 - nm);
        m = nm;
    }
    float inv = 1.f / (l + 1e-16f);
    for (int it = 0; it < 8 && it * 8 < degN; it++) {
        int idx = it * 64 + lane;
        al[w][idx] = __expf(al[w][idx] - m) * inv;
    }
    int hb = lane >> 3;
    float mB = __shfl(m, hb);
    float invB = __shfl(inv, hb);
    float advB = __shfl(adv, hb);
    float acc = 0.f;
    for (int j = beg; j < end; j++) {
        int e0 = j - beg;
        float a;
        int s;
        if (e0 < 64) {
            a = al[w][e0 * 8 + hb];
            s = sc[w][e0];
        } else {
            s = csr[j];
            float v = as1[s * 8 + hb] + advB;
            a = __expf(LRELU(v) - mB) * invB;
        }
        acc += a * h1[(size_t)s * 64 + lane];
    }
    float val = acc + b1[lane];
    float zv = val > 0.f ? val : __expf(val) - 1.f;  // ELU
    z[(size_t)node * 64 + lane] = zv;
    zr[w][lane] = zv;
    if (lane < 16) {
        int hh = lane & 7;
        const float* wf = wfold + (lane < 8 ? 0 : 512);
        float sdot = 0.f;
        for (int k = 0; k < 64; k++) sdot += zr[w][k] * wf[k * 8 + hh];
        if (lane < 8) as2[node * 8 + hh] = sdot;
        else          ad2[node * 8 + hh] = sdot;
    }
}

// ================= fused layer-2 attention+aggregation + output GEMM + log_softmax =================
// 512 threads = 8 waves = 8 nodes/block. Phase A: one wave per node computes
// attention-weighted agg[8 heads][64 ch] (alpha LDS slab reused in-place as agg).
// Phase B: block-wide per-head GEMM vs W2 + bias + log_softmax, straight from LDS.

__global__ __launch_bounds__(512) void k_attn2out(const int* offs, const int* csr,
                                                  const float* __restrict__ zt,
                                                  const float* __restrict__ as2,
                                                  const float* __restrict__ ad2,
                                                  const float* __restrict__ W2,
                                                  const float* __restrict__ b2,
                                                  float* out, int N) {
    __shared__ float sa[8][512];  // per-wave: alpha (phase A) then agg (phase B)
    __shared__ int   sc[8][64];
    __shared__ float red[8][4];
    int w = threadIdx.x >> 6, lane = threadIdx.x & 63;
    int n0 = blockIdx.x * 8;
    int node = n0 + w;

    // ---- phase A: attention + aggregation for this wave's node ----
    float acc[8] = {0.f, 0.f, 0.f, 0.f, 0.f, 0.f, 0.f, 0.f};
    if (node < N) {
        int el = lane >> 3, h = lane & 7;
        int beg = offs[node], end = offs[node + 1];
        int degN = end - beg;
        float adv = ad2[node * 8 + h];
        float m = -1e30f, l = 0.f;
        for (int it = 0; it * 8 < degN; it++) {
            int j = beg + it * 8 + el;
            float e = -1e30f;
            int s = 0;
            if (j < end) {
                s = csr[j];
                float v = as2[s * 8 + h] + adv;
                e = LRELU(v);
            }
            if (it < 8) {
                sa[w][it * 64 + lane] = e;
                if (h == 0 && j < end) sc[w][it * 8 + el] = s;
            }
            float nm = fmaxf(m, e);
            l = l * __expf(m - nm) + ((j < end) ? __expf(e - nm) : 0.f);
            m = nm;
        }
#pragma unroll
        for (int off = 8; off < 64; off <<= 1) {
            float m2 = __shfl_xor(m, off), l2 = __shfl_xor(l, off);
            float nm = fmaxf(m, m2);
            l = l * __expf(m - nm) + l2 * __expf(m2 - nm);
            m = nm;
        }
        float inv = 1.f / (l + 1e-16f);
        for (int it = 0; it < 8 && it * 8 < degN; it++) {
            int idx = it * 64 + lane;
            sa[w][idx] = __expf(sa[w][idx] - m) * inv;
        }
        float mH[8], invH[8], advH[8];
#pragma unroll
        for (int hh = 0; hh < 8; hh++) {
            mH[hh] = __shfl(m, hh);
            invH[hh] = __shfl(inv, hh);
            advH[hh] = __shfl(adv, hh);
        }
        for (int j = beg; j < end; j++) {
            int e0 = j - beg;
            float a[8];
            int s;
            if (e0 < 64) {
                float4 a0 = *(const float4*)&sa[w][e0 * 8];
                float4 a1 = *(const float4*)&sa[w][e0 * 8 + 4];
                a[0] = a0.x; a[1] = a0.y; a[2] = a0.z; a[3] = a0.w;
                a[4] = a1.x; a[5] = a1.y; a[6] = a1.z; a[7] = a1.w;
                s = sc[w][e0];
            } else {
                s = csr[j];
#pragma unroll
                for (int hh = 0; hh < 8; hh++) {
                    float v = as2[s * 8 + hh] + advH[hh];
                    a[hh] = __expf(LRELU(v) - mH[hh]) * invH[hh];
                }
            }
            float zvv = zt[(size_t)s * 64 + lane];
#pragma unroll
            for (int hh = 0; hh < 8; hh++) acc[hh] += a[hh] * zvv;
        }
    }
    // wave-private slab: done reading alpha, overwrite with agg (no cross-wave hazard)
#pragma unroll
    for (int hh = 0; hh < 8; hh++) sa[w][hh * 64 + lane] = acc[hh];
    __syncthreads();

    // ---- phase B: GEMM + bias + log_softmax; thread owns 4 channels x 4 nodes ----
    int t = threadIdx.x;
    int g = t >> 8;        // node group: 0 -> nodes 0..3, 1 -> nodes 4..7
    int tt = t & 255;
    int c0 = tt * 4;       // 4 consecutive channels, same head
    int hh2 = tt >> 5;
    float4 acc4[4];
    float4 bb = *(const float4*)&b2[c0];
#pragma unroll
    for (int mi = 0; mi < 4; mi++) acc4[mi] = bb;
    for (int k0 = 0; k0 < 64; k0 += 4) {
        float4 w0 = *(const float4*)&W2[(size_t)(k0 + 0) * 1024 + c0];
        float4 w1 = *(const float4*)&W2[(size_t)(k0 + 1) * 1024 + c0];
        float4 w2 = *(const float4*)&W2[(size_t)(k0 + 2) * 1024 + c0];
        float4 w3 = *(const float4*)&W2[(size_t)(k0 + 3) * 1024 + c0];
#pragma unroll
        for (int mi = 0; mi < 4; mi++) {
            float4 a = *(const float4*)&sa[g * 4 + mi][hh2 * 64 + k0];
            acc4[mi].x += a.x * w0.x + a.y * w1.x + a.z * w2.x + a.w * w3.x;
            acc4[mi].y += a.x * w0.y + a.y * w1.y + a.z * w2.y + a.w * w3.y;
            acc4[mi].z += a.x * w0.z + a.y * w1.z + a.z * w2.z + a.w * w3.z;
            acc4[mi].w += a.x * w0.w + a.y * w1.w + a.z * w2.w + a.w * w3.w;
        }
    }
    int wave = t >> 6;  // 0..7; waves 0-3 = group 0, waves 4-7 = group 1
    float gmax[4], logZ[4];
#pragma unroll
    for (int mi = 0; mi < 4; mi++) {
        float v = fmaxf(fmaxf(acc4[mi].x, acc4[mi].y), fmaxf(acc4[mi].z, acc4[mi].w));
        for (int off = 32; off; off >>= 1) v = fmaxf(v, __shfl_xor(v, off));
        if (lane == 0) red[wave][mi] = v;
    }
    __syncthreads();
#pragma unroll
    for (int mi = 0; mi < 4; mi++)
        gmax[mi] = fmaxf(fmaxf(red[g * 4 + 0][mi], red[g * 4 + 1][mi]),
                         fmaxf(red[g * 4 + 2][mi], red[g * 4 + 3][mi]));
    __syncthreads();
#pragma unroll
    for (int mi = 0; mi < 4; mi++) {
        float v = __expf(acc4[mi].x - gmax[mi]) + __expf(acc4[mi].y - gmax[mi]) +
                  __expf(acc4[mi].z - gmax[mi]) + __expf(acc4[mi].w - gmax[mi]);
        for (int off = 32; off; off >>= 1) v += __shfl_xor(v, off);
        if (lane == 0) red[wave][mi] = v;
    }
    __syncthreads();
#pragma unroll
    for (int mi = 0; mi < 4; mi++) {
        float gs = red[g * 4 + 0][mi] + red[g * 4 + 1][mi] +
                   red[g * 4 + 2][mi] + red[g * 4 + 3][mi];
        logZ[mi] = gmax[mi] + __logf(gs);
    }
#pragma unroll
    for (int mi = 0; mi < 4; mi++) {
        int n = n0 + g * 4 + mi;
        if (n >= N) continue;
        float4 o;
        o.x = acc4[mi].x - logZ[mi];
        o.y = acc4[mi].y - logZ[mi];
        o.z = acc4[mi].z - logZ[mi];
        o.w = acc4[mi].w - logZ[mi];
        *(float4*)&out[(size_t)n * 1024 + c0] = o;
    }
}

// ================= launch =================

extern "C" void kernel_launch(void* const* d_in, const int* in_sizes, int n_in,
                              void* d_out, int out_size, void* d_ws, size_t ws_size,
                              hipStream_t stream) {
    const float* x      = (const float*)d_in[0];
    const int*   ei     = (const int*)d_in[1];
    const float* W1     = (const float*)d_in[2];
    const float* a_src1 = (const float*)d_in[3];
    const float* a_dst1 = (const float*)d_in[4];
    const float* b1     = (const float*)d_in[5];
    const float* W2     = (const float*)d_in[6];
    const float* a_src2 = (const float*)d_in[7];
    const float* a_dst2 = (const float*)d_in[8];
    const float* b2     = (const float*)d_in[9];
    float* out = (float*)d_out;

    int N = in_sizes[0] / 128;
    int E = in_sizes[1] / 2;
    const int* src = ei;
    const int* dst = ei + E;

    char* p = (char*)d_ws;
    auto carve = [&](size_t bytes) {
        void* r = (void*)p;
        p += (bytes + 255) & ~(size_t)255;
        return r;
    };
    int*   deg    = (int*)carve((size_t)N * 4);
    int*   offs   = (int*)carve((size_t)(N + 1) * 4);
    int*   cursor = (int*)carve((size_t)N * 4);
    int*   done   = (int*)carve(256);
    int*   csr    = (int*)carve((size_t)(E + N) * 4);
    float* h1     = (float*)carve((size_t)N * 64 * 4);
    float* as1    = (float*)carve((size_t)N * 8 * 4);
    float* ad1    = (float*)carve((size_t)N * 8 * 4);
    float* z      = (float*)carve((size_t)N * 64 * 4);
    float* as2    = (float*)carve((size_t)N * 8 * 4);
    float* ad2    = (float*)carve((size_t)N * 8 * 4);
    float* wfold  = (float*)carve((size_t)1024 * 4);

    int GB = (N + 15) / 16;
    int DB = (N + 255) / 256;
    int HB = (E + 255) / 256;
    int nb4 = (N + 3) / 4;

    // D1: gemm1 + fold + deg/done init
    k_front<<<GB + 64 + DB, 256, 0, stream>>>(x, W1, a_src1, a_dst1, W2, a_src2, a_dst2,
                                              h1, as1, ad1, wfold, deg, done, N, GB);
    // D2: histogram + last-block exclusive scan
    k_histscan<<<HB, 256, 0, stream>>>(src, dst, deg, done, offs, cursor, E, N);
    // D3: CSR fill
    k_fill<<<(E + N + 255) / 256, 256, 0, stream>>>(src, dst, cursor, csr, E, N);
    // D4: layer-1 fused attention+aggregation
    k_attn1<<<nb4, 256, 0, stream>>>(offs, csr, h1, as1, ad1, b1, wfold, z, as2, ad2, N);
    // D5: layer-2 attention+aggregation + output GEMM + log_softmax
    k_attn2out<<<(N + 7) / 8, 512, 0, stream>>>(offs, csr, z, as2, ad2, W2, b2, out, N);
}

// Round 8
// 247.130 us; speedup vs baseline: 2.6349x; 2.6349x over previous
//
#include <hip/hip_runtime.h>
#include <cstddef>
#include <cstdint>

#define LRELU(v) ((v) > 0.f ? (v) : 0.2f * (v))

// ================= K1: fused gemm1 + fold(W2,a2) + deg/done init =================

__global__ __launch_bounds__(256) void k_front(const float* __restrict__ x,
                                               const float* __restrict__ W1,
                                               const float* __restrict__ a_src1,
                                               const float* __restrict__ a_dst1,
                                               const float* __restrict__ W2,
                                               const float* __restrict__ a_src2,
                                               const float* __restrict__ a_dst2,
                                               float* h1, float* as1, float* ad1,
                                               float* wfold, int* deg, int* done,
                                               int N, int GB) {
    int t = threadIdx.x;
    int b = blockIdx.x;
    if (b < GB) {
        __shared__ float xs[16][128];
        int n0 = b * 16;
#pragma unroll
        for (int i = 0; i < 2; i++) {
            int idx = (t + i * 256) * 4;
            int r = idx >> 7, c = idx & 127;
            int n = n0 + r;
            float4 v = make_float4(0.f, 0.f, 0.f, 0.f);
            if (n < N) v = *(const float4*)&x[(size_t)n * 128 + c];
            *(float4*)&xs[r][c] = v;
        }
        __syncthreads();
        int wv = t >> 6, lane = t & 63;
        int m0 = wv * 4;
        float acc[4] = {0.f, 0.f, 0.f, 0.f};
        for (int k0 = 0; k0 < 128; k0 += 4) {
            float w0 = W1[(k0 + 0) * 64 + lane];
            float w1 = W1[(k0 + 1) * 64 + lane];
            float w2 = W1[(k0 + 2) * 64 + lane];
            float w3 = W1[(k0 + 3) * 64 + lane];
#pragma unroll
            for (int mi = 0; mi < 4; mi++) {
                float4 a = *(const float4*)&xs[m0 + mi][k0];
                acc[mi] += a.x * w0 + a.y * w1 + a.z * w2 + a.w * w3;
            }
        }
        float was = a_src1[lane], wad = a_dst1[lane];
#pragma unroll
        for (int mi = 0; mi < 4; mi++) {
            int n = n0 + m0 + mi;
            if (n >= N) break;
            h1[(size_t)n * 64 + lane] = acc[mi];
            float ps = acc[mi] * was, pd = acc[mi] * wad;
            ps += __shfl_xor(ps, 1); ps += __shfl_xor(ps, 2); ps += __shfl_xor(ps, 4);
            pd += __shfl_xor(pd, 1); pd += __shfl_xor(pd, 2); pd += __shfl_xor(pd, 4);
            if ((lane & 7) == 0) {
                as1[n * 8 + (lane >> 3)] = ps;
                ad1[n * 8 + (lane >> 3)] = pd;
            }
        }
    } else if (b < GB + 64) {
        int k = b - GB;
        int c0 = t * 4;
        int h = t >> 5;
        float4 w = *(const float4*)&W2[(size_t)k * 1024 + c0];
        float4 s4 = *(const float4*)&a_src2[c0];
        float4 d4 = *(const float4*)&a_dst2[c0];
        float ss = w.x * s4.x + w.y * s4.y + w.z * s4.z + w.w * s4.w;
        float sd = w.x * d4.x + w.y * d4.y + w.z * d4.z + w.w * d4.w;
#pragma unroll
        for (int off = 1; off <= 16; off <<= 1) {
            ss += __shfl_xor(ss, off);
            sd += __shfl_xor(sd, off);
        }
        if ((t & 31) == 0) {
            wfold[k * 8 + h] = ss;
            wfold[512 + k * 8 + h] = sd;
        }
    } else {
        int i = (b - GB - 64) * 256 + t;
        if (i < N) deg[i] = 1;  // self-loop
        if (b == GB + 64 && t == 0) *done = 0;
    }
}

// ================= histogram + (last block) exclusive scan =================

__global__ __launch_bounds__(256) void k_histscan(const int* __restrict__ src,
                                                  const int* __restrict__ dst,
                                                  int* deg, int* done,
                                                  int* offs, int* cursor, int E, int N) {
    __shared__ int part[256];
    __shared__ int islast;
    int t = threadIdx.x;
    int e = blockIdx.x * 256 + t;
    if (e < E) {
        int s = src[e], d = dst[e];
        if (s != d) atomicAdd(&deg[d], 1);  // masked self-edges dropped
    }
    __syncthreads();
    if (t == 0) {
        int old = __hip_atomic_fetch_add(done, 1, __ATOMIC_ACQ_REL, __HIP_MEMORY_SCOPE_AGENT);
        islast = (old == (int)gridDim.x - 1);
    }
    __syncthreads();
    if (!islast) return;
    int chunk = (N + 255) >> 8;
    int start = t * chunk;
    int s = 0;
    for (int i = 0; i < chunk; i++) {
        int idx = start + i;
        if (idx < N)
            s += __hip_atomic_load(&deg[idx], __ATOMIC_RELAXED, __HIP_MEMORY_SCOPE_AGENT);
    }
    part[t] = s;
    __syncthreads();
    for (int off = 1; off < 256; off <<= 1) {
        int v = (t >= off) ? part[t - off] : 0;
        __syncthreads();
        part[t] += v;
        __syncthreads();
    }
    int run = part[t] - s;
    for (int i = 0; i < chunk; i++) {
        int idx = start + i;
        if (idx < N) {
            int d = __hip_atomic_load(&deg[idx], __ATOMIC_RELAXED, __HIP_MEMORY_SCOPE_AGENT);
            offs[idx] = run;
            cursor[idx] = run;
            run += d;
        }
    }
    if (t == 255) offs[N] = part[255];
}

// ================= CSR fill =================

__global__ void k_fill(const int* src, const int* dst, int* cursor, int* csr, int E, int N) {
    int e = blockIdx.x * blockDim.x + threadIdx.x;
    if (e < E) {
        int s = src[e], d = dst[e];
        if (s != d) {
            int pos = atomicAdd(&cursor[d], 1);
            csr[pos] = s;
        }
    } else if (e < E + N) {
        int i = e - E;
        int pos = atomicAdd(&cursor[i], 1);
        csr[pos] = i;
    }
}

// ================= fused attention+aggregation, layer 1 =================

__global__ __launch_bounds__(256) void k_attn1(const int* offs, const int* csr,
                                               const float* __restrict__ h1,
                                               const float* __restrict__ as1,
                                               const float* __restrict__ ad1,
                                               const float* __restrict__ b1,
                                               const float* __restrict__ wfold,
                                               float* z, float* as2, float* ad2, int N) {
    __shared__ float al[4][512];
    __shared__ int   sc[4][64];
    __shared__ float zr[4][64];
    int w = threadIdx.x >> 6, lane = threadIdx.x & 63;
    int node = blockIdx.x * 4 + w;
    if (node >= N) return;
    int el = lane >> 3, h = lane & 7;
    int beg = offs[node], end = offs[node + 1];
    int degN = end - beg;
    float adv = ad1[node * 8 + h];
    float m = -1e30f, l = 0.f;
    for (int it = 0; it * 8 < degN; it++) {
        int j = beg + it * 8 + el;
        float e = -1e30f;
        int s = 0;
        if (j < end) {
            s = csr[j];
            float v = as1[s * 8 + h] + adv;
            e = LRELU(v);
        }
        if (it < 8) {
            al[w][it * 64 + lane] = e;
            if (h == 0 && j < end) sc[w][it * 8 + el] = s;
        }
        float nm = fmaxf(m, e);
        l = l * __expf(m - nm) + ((j < end) ? __expf(e - nm) : 0.f);
        m = nm;
    }
#pragma unroll
    for (int off = 8; off < 64; off <<= 1) {
        float m2 = __shfl_xor(m, off), l2 = __shfl_xor(l, off);
        float nm = fmaxf(m, m2);
        l = l * __expf(m - nm) + l2 * __expf(m2 - nm);
        m = nm;
    }
    float inv = 1.f / (l + 1e-16f);
    for (int it = 0; it < 8 && it * 8 < degN; it++) {
        int idx = it * 64 + lane;
        al[w][idx] = __expf(al[w][idx] - m) * inv;
    }
    int hb = lane >> 3;
    float mB = __shfl(m, hb);
    float invB = __shfl(inv, hb);
    float advB = __shfl(adv, hb);
    float acc = 0.f;
    for (int j = beg; j < end; j++) {
        int e0 = j - beg;
        float a;
        int s;
        if (e0 < 64) {
            a = al[w][e0 * 8 + hb];
            s = sc[w][e0];
        } else {
            s = csr[j];
            float v = as1[s * 8 + hb] + advB;
            a = __expf(LRELU(v) - mB) * invB;
        }
        acc += a * h1[(size_t)s * 64 + lane];
    }
    float val = acc + b1[lane];
    float zv = val > 0.f ? val : __expf(val) - 1.f;  // ELU
    z[(size_t)node * 64 + lane] = zv;
    zr[w][lane] = zv;
    if (lane < 16) {
        int hh = lane & 7;
        const float* wf = wfold + (lane < 8 ? 0 : 512);
        float sdot = 0.f;
        for (int k = 0; k < 64; k++) sdot += zr[w][k] * wf[k * 8 + hh];
        if (lane < 8) as2[node * 8 + hh] = sdot;
        else          ad2[node * 8 + hh] = sdot;
    }
}

// ================= fused attention+aggregation, layer 2 =================

__global__ __launch_bounds__(256) void k_attn2(const int* offs, const int* csr,
                                               const float* __restrict__ zt,
                                               const float* __restrict__ as2,
                                               const float* __restrict__ ad2,
                                               float* agg, int N) {
    __shared__ float al[4][512];
    __shared__ int   sc[4][64];
    int w = threadIdx.x >> 6, lane = threadIdx.x & 63;
    int node = blockIdx.x * 4 + w;
    if (node >= N) return;
    int el = lane >> 3, h = lane & 7;
    int beg = offs[node], end = offs[node + 1];
    int degN = end - beg;
    float adv = ad2[node * 8 + h];
    float m = -1e30f, l = 0.f;
    for (int it = 0; it * 8 < degN; it++) {
        int j = beg + it * 8 + el;
        float e = -1e30f;
        int s = 0;
        if (j < end) {
            s = csr[j];
            float v = as2[s * 8 + h] + adv;
            e = LRELU(v);
        }
        if (it < 8) {
            al[w][it * 64 + lane] = e;
            if (h == 0 && j < end) sc[w][it * 8 + el] = s;
        }
        float nm = fmaxf(m, e);
        l = l * __expf(m - nm) + ((j < end) ? __expf(e - nm) : 0.f);
        m = nm;
    }
#pragma unroll
    for (int off = 8; off < 64; off <<= 1) {
        float m2 = __shfl_xor(m, off), l2 = __shfl_xor(l, off);
        float nm = fmaxf(m, m2);
        l = l * __expf(m - nm) + l2 * __expf(m2 - nm);
        m = nm;
    }
    float inv = 1.f / (l + 1e-16f);
    for (int it = 0; it < 8 && it * 8 < degN; it++) {
        int idx = it * 64 + lane;
        al[w][idx] = __expf(al[w][idx] - m) * inv;
    }
    float mH[8], invH[8], advH[8];
#pragma unroll
    for (int hh = 0; hh < 8; hh++) {
        mH[hh] = __shfl(m, hh);
        invH[hh] = __shfl(inv, hh);
        advH[hh] = __shfl(adv, hh);
    }
    float acc[8] = {0.f, 0.f, 0.f, 0.f, 0.f, 0.f, 0.f, 0.f};
    for (int j = beg; j < end; j++) {
        int e0 = j - beg;
        float a[8];
        int s;
        if (e0 < 64) {
            float4 a0 = *(const float4*)&al[w][e0 * 8];
            float4 a1 = *(const float4*)&al[w][e0 * 8 + 4];
            a[0] = a0.x; a[1] = a0.y; a[2] = a0.z; a[3] = a0.w;
            a[4] = a1.x; a[5] = a1.y; a[6] = a1.z; a[7] = a1.w;
            s = sc[w][e0];
        } else {
            s = csr[j];
#pragma unroll
            for (int hh = 0; hh < 8; hh++) {
                float v = as2[s * 8 + hh] + advH[hh];
                a[hh] = __expf(LRELU(v) - mH[hh]) * invH[hh];
            }
        }
        float zvv = zt[(size_t)s * 64 + lane];
#pragma unroll
        for (int hh = 0; hh < 8; hh++) acc[hh] += a[hh] * zvv;
    }
#pragma unroll
    for (int hh = 0; hh < 8; hh++)
        agg[(size_t)node * 512 + hh * 64 + lane] = acc[hh];
}

// ================= final per-head GEMM + bias + log_softmax (8 nodes/block) =================
// R4-proven shape: 1250 blocks, 16.9 KB LDS, ~10 us. 16-node variant regressed
// to 63 us (12% occupancy, latency-bound) — do not re-widen.

__global__ __launch_bounds__(256) void k_out(const float* __restrict__ agg,
                                             const float* __restrict__ W2,
                                             const float* __restrict__ b2,
                                             float* out, int N) {
    __shared__ float sa[4096];  // 8 nodes x 512
    __shared__ float red[4][8];
    int t = threadIdx.x;
    int n0 = blockIdx.x * 8;
#pragma unroll
    for (int i = 0; i < 4; i++) {
        int idx = (t + i * 256) * 4;
        int r = idx >> 9, c = idx & 511;
        int n = n0 + r;
        float4 v = make_float4(0.f, 0.f, 0.f, 0.f);
        if (n < N) v = *(const float4*)&agg[(size_t)n * 512 + c];
        *(float4*)&sa[idx] = v;
    }
    __syncthreads();
    int c0 = t * 4;
    int hh = t >> 5;
    float4 acc[8];
    float4 bb = *(const float4*)&b2[c0];
#pragma unroll
    for (int mi = 0; mi < 8; mi++) acc[mi] = bb;
    for (int k0 = 0; k0 < 64; k0 += 4) {
        float4 w0 = *(const float4*)&W2[(size_t)(k0 + 0) * 1024 + c0];
        float4 w1 = *(const float4*)&W2[(size_t)(k0 + 1) * 1024 + c0];
        float4 w2 = *(const float4*)&W2[(size_t)(k0 + 2) * 1024 + c0];
        float4 w3 = *(const float4*)&W2[(size_t)(k0 + 3) * 1024 + c0];
#pragma unroll
        for (int mi = 0; mi < 8; mi++) {
            float4 a = *(const float4*)&sa[mi * 512 + hh * 64 + k0];
            acc[mi].x += a.x * w0.x + a.y * w1.x + a.z * w2.x + a.w * w3.x;
            acc[mi].y += a.x * w0.y + a.y * w1.y + a.z * w2.y + a.w * w3.y;
            acc[mi].z += a.x * w0.z + a.y * w1.z + a.z * w2.z + a.w * w3.z;
            acc[mi].w += a.x * w0.w + a.y * w1.w + a.z * w2.w + a.w * w3.w;
        }
    }
    int wave = t >> 6, lane = t & 63;
    float gmax[8], logZ[8];
#pragma unroll
    for (int mi = 0; mi < 8; mi++) {
        float v = fmaxf(fmaxf(acc[mi].x, acc[mi].y), fmaxf(acc[mi].z, acc[mi].w));
        for (int off = 32; off; off >>= 1) v = fmaxf(v, __shfl_xor(v, off));
        if (lane == 0) red[wave][mi] = v;
    }
    __syncthreads();
#pragma unroll
    for (int mi = 0; mi < 8; mi++)
        gmax[mi] = fmaxf(fmaxf(red[0][mi], red[1][mi]), fmaxf(red[2][mi], red[3][mi]));
    __syncthreads();
#pragma unroll
    for (int mi = 0; mi < 8; mi++) {
        float v = __expf(acc[mi].x - gmax[mi]) + __expf(acc[mi].y - gmax[mi]) +
                  __expf(acc[mi].z - gmax[mi]) + __expf(acc[mi].w - gmax[mi]);
        for (int off = 32; off; off >>= 1) v += __shfl_xor(v, off);
        if (lane == 0) red[wave][mi] = v;
    }
    __syncthreads();
#pragma unroll
    for (int mi = 0; mi < 8; mi++) {
        float gs = red[0][mi] + red[1][mi] + red[2][mi] + red[3][mi];
        logZ[mi] = gmax[mi] + __logf(gs);
    }
#pragma unroll
    for (int mi = 0; mi < 8; mi++) {
        int n = n0 + mi;
        if (n >= N) continue;
        float4 o;
        o.x = acc[mi].x - logZ[mi];
        o.y = acc[mi].y - logZ[mi];
        o.z = acc[mi].z - logZ[mi];
        o.w = acc[mi].w - logZ[mi];
        *(float4*)&out[(size_t)n * 1024 + c0] = o;
    }
}

// ================= launch =================

extern "C" void kernel_launch(void* const* d_in, const int* in_sizes, int n_in,
                              void* d_out, int out_size, void* d_ws, size_t ws_size,
                              hipStream_t stream) {
    const float* x      = (const float*)d_in[0];
    const int*   ei     = (const int*)d_in[1];
    const float* W1     = (const float*)d_in[2];
    const float* a_src1 = (const float*)d_in[3];
    const float* a_dst1 = (const float*)d_in[4];
    const float* b1     = (const float*)d_in[5];
    const float* W2     = (const float*)d_in[6];
    const float* a_src2 = (const float*)d_in[7];
    const float* a_dst2 = (const float*)d_in[8];
    const float* b2     = (const float*)d_in[9];
    float* out = (float*)d_out;

    int N = in_sizes[0] / 128;
    int E = in_sizes[1] / 2;
    const int* src = ei;
    const int* dst = ei + E;

    char* p = (char*)d_ws;
    auto carve = [&](size_t bytes) {
        void* r = (void*)p;
        p += (bytes + 255) & ~(size_t)255;
        return r;
    };
    int*   deg    = (int*)carve((size_t)N * 4);
    int*   offs   = (int*)carve((size_t)(N + 1) * 4);
    int*   cursor = (int*)carve((size_t)N * 4);
    int*   done   = (int*)carve(256);
    int*   csr    = (int*)carve((size_t)(E + N) * 4);
    float* h1     = (float*)carve((size_t)N * 64 * 4);
    float* as1    = (float*)carve((size_t)N * 8 * 4);
    float* ad1    = (float*)carve((size_t)N * 8 * 4);
    float* z      = (float*)carve((size_t)N * 64 * 4);
    float* as2    = (float*)carve((size_t)N * 8 * 4);
    float* ad2    = (float*)carve((size_t)N * 8 * 4);
    float* wfold  = (float*)carve((size_t)1024 * 4);
    float* agg    = (float*)carve((size_t)N * 512 * 4);

    int GB = (N + 15) / 16;
    int DB = (N + 255) / 256;
    int HB = (E + 255) / 256;
    int nb4 = (N + 3) / 4;

    // D1: gemm1 + fold + deg/done init
    k_front<<<GB + 64 + DB, 256, 0, stream>>>(x, W1, a_src1, a_dst1, W2, a_src2, a_dst2,
                                              h1, as1, ad1, wfold, deg, done, N, GB);
    // D2: histogram + last-block exclusive scan
    k_histscan<<<HB, 256, 0, stream>>>(src, dst, deg, done, offs, cursor, E, N);
    // D3: CSR fill
    k_fill<<<(E + N + 255) / 256, 256, 0, stream>>>(src, dst, cursor, csr, E, N);
    // D4: layer-1 fused attention+aggregation
    k_attn1<<<nb4, 256, 0, stream>>>(offs, csr, h1, as1, ad1, b1, wfold, z, as2, ad2, N);
    // D5: layer-2 fused attention+aggregation
    k_attn2<<<nb4, 256, 0, stream>>>(offs, csr, z, as2, ad2, agg, N);
    // D6: output GEMM + log_softmax
    k_out<<<(N + 7) / 8, 256, 0, stream>>>(agg, W2, b2, out, N);
}